// Round 1
// baseline (446.692 us; speedup 1.0000x reference)
//
#include <hip/hip_runtime.h>
#include <math.h>

#define NL 5
#define KM 5
#define MF 50
#define BATCH_ 131072
#define XROW (NL + 2*MF)      /* 105 */
#define SROW (KM*(2*NL+1))    /* 55  */
#define MU_F 1.2566370614359172e-06f
#define LOG2PI_F 1.8378770664093453f

__device__ __forceinline__ float softplusf_(float v) {
    return fmaxf(v, 0.0f) + log1pf(expf(-fabsf(v)));
}

// Block-wide sum of v, then one double atomicAdd per block.
// __shared__ in a device function has static duration; the leading
// __syncthreads() protects against WAR with a previous call's read.
__device__ __forceinline__ void block_add(float v, double* target) {
    __shared__ float red_[4];
    #pragma unroll
    for (int off = 32; off > 0; off >>= 1) v += __shfl_down(v, off, 64);
    __syncthreads();
    if ((threadIdx.x & 63) == 0) red_[threadIdx.x >> 6] = v;
    __syncthreads();
    if (threadIdx.x == 0)
        atomicAdd(target, (double)(red_[0] + red_[1] + red_[2] + red_[3]));
}

// Per-batch: mixture params, component draw, truncated-normal samples,
// lq (entropy term), and the 9 frequency-independent forward-model constants:
// pr[0]=sqrt(MU*res4/2); pr[1+j]=2*th_j*sqrt(MU/(2 r_j)); pr[5+j]=sqrt(MU*r_j/2)
__device__ __forceinline__ float prep_one(
    int b, const float* __restrict__ x, const float* __restrict__ s,
    const float* __restrict__ u_cat, const float* __restrict__ u_trunc,
    float pr[9])
{
    const float* srow = s + (size_t)b * SROW;
    float loc[KM][NL], sig[KM][NL], pro[KM];
    float sqsum = 0.0f;
    #pragma unroll
    for (int k = 0; k < KM; ++k) {
        float v = srow[k*11 + 10];
        pro[k] = v * v;
        sqsum += pro[k];
    }
    float isq = 1.0f / sqsum;
    #pragma unroll
    for (int k = 0; k < KM; ++k) pro[k] *= isq;
    #pragma unroll
    for (int k = 0; k < KM; ++k) {
        #pragma unroll
        for (int i = 0; i < NL; ++i) {
            loc[k][i] = 4.0f / (1.0f + expf(-srow[k*11 + i]));
            sig[k][i] = softplusf_(srow[k*11 + 5 + i]);
        }
    }
    // component draw: comp = clip(#{k : u > cum_k}, 0, K-1)
    float u = u_cat[b];
    float cum = 0.0f; int cnt = 0;
    #pragma unroll
    for (int k = 0; k < KM; ++k) { cum += pro[k]; if (u > cum) ++cnt; }
    int comp = cnt < KM-1 ? cnt : KM-1;
    float ls[NL], ss[NL];
    #pragma unroll
    for (int i = 0; i < NL; ++i) { ls[i] = loc[0][i]; ss[i] = sig[0][i]; }
    #pragma unroll
    for (int k = 1; k < KM; ++k) {
        bool sel = (k == comp);
        #pragma unroll
        for (int i = 0; i < NL; ++i) {
            ls[i] = sel ? loc[k][i] : ls[i];
            ss[i] = sel ? sig[k][i] : ss[i];
        }
    }
    // truncated-normal samples
    float smp[NL];
    #pragma unroll
    for (int i = 0; i < NL; ++i) {
        float a  = (0.1f - ls[i]) / ss[i];
        float bb = (3.9f - ls[i]) / ss[i];
        float Fa = normcdff(a), Fb = normcdff(bb);
        float p  = Fa + u_trunc[(size_t)b*NL + i] * (Fb - Fa);
        p = fminf(fmaxf(p, 0.0f), 1.0f);
        float z  = normcdfinvf(p);
        float sq = ls[i] + ss[i] * z;          // +-inf tails clip below
        smp[i] = fminf(fmaxf(sq, 0.1f), 3.9f);
    }
    // lq = logsumexp_k( log pro_k + sum_i trunc-normal logpdf )
    float vals[KM]; float mx = -INFINITY;
    #pragma unroll
    for (int k = 0; k < KM; ++k) {
        float acc = logf(pro[k]);
        #pragma unroll
        for (int i = 0; i < NL; ++i) {
            float l = loc[k][i], sg = sig[k][i];
            float zc = (smp[i] - l) / sg;
            float a_ = (0.0f - l) / sg;
            float b_ = (4.0f - l) / sg;
            float Z  = normcdff(b_) - normcdff(a_);   // >= ~0.2, safe for log
            acc += -0.5f*zc*zc - 0.5f*LOG2PI_F - logf(sg) - logf(Z);
        }
        vals[k] = acc;
        mx = fmaxf(mx, acc);
    }
    float se = 0.0f;
    #pragma unroll
    for (int k = 0; k < KM; ++k) se += expf(vals[k] - mx);
    float lq = mx + logf(se);
    // forward-model constants (sqrt(w) factored out)
    float r4 = exp10f(smp[NL-1]);
    pr[0] = sqrtf(0.5f * MU_F * r4);
    #pragma unroll
    for (int j = 0; j < NL-1; ++j) {
        float r   = exp10f(smp[j]);
        float th  = x[(size_t)b*XROW + j];
        float sqc = sqrtf(0.5f * MU_F / r);
        pr[1+j] = 2.0f * th * sqc;
        pr[5+j] = sqc * r;
    }
    return lq;
}

// One (batch, freq): 4-layer MT recursion + the two log-lik terms.
__device__ __forceinline__ float fwd_one(int b, int m,
    const float* __restrict__ x, const float pr[9])
{
    float ex = fmaf((float)m, 5.0f/49.0f, -2.0f);
    float w  = 6.283185307179586f * exp10f(ex);
    float sw = sqrtf(w);
    float ZR = sw * pr[0];
    float ZC = ZR;
    #pragma unroll
    for (int j = NL-2; j >= 0; --j) {
        float wj = sw * pr[5+j];
        float t  = sw * pr[1+j];      // t <= ~0.11, tiny args
        float e  = expf(-t);
        float st, ct;
        sincosf(t, &st, &ct);
        float ejR = e * ct;
        float ejC = -e * st;
        float s0 = wj + ZR, s1 = wj + ZC;
        float den = s0*s0 + s1*s1;
        float rjR = (2.0f*wj*wj - ZR*ZR - ZC*ZC) / den;
        float rjC = (2.0f*wj*(ZR - ZC)) / den;
        float reR = rjR*ejR - rjC*ejC;
        float reC = rjR*ejC + rjC*ejR;
        float o = 1.0f + reR;
        float den2 = o*o + reC*reC;
        float auxR = (1.0f - reR*reR - reC*reC) / den2;
        float auxC = (-2.0f*reC) / den2;
        ZR = wj * (auxR - auxC);
        ZC = wj * (auxC + auxR);
    }
    float absZ2 = ZR*ZR + ZC*ZC;
    float aRes = log10f(absZ2 / (MU_F * w));
    float ph   = atan2f(ZC, ZR);
    float oA = x[(size_t)b*XROW + NL + m];
    float oP = x[(size_t)b*XROW + NL + MF + m];
    float scA = fabsf(0.03f * aRes);
    float vA  = (aRes - oA) / scA;
    float scP = fabsf(0.03f * ph);
    float vP  = (ph - oP) / scP;
    return -0.5f*vA*vA - logf(scA) - 0.5f*vP*vP - logf(scP) - LOG2PI_F;
}

__global__ void __launch_bounds__(256) k_prep(
    const float* __restrict__ x, const float* __restrict__ s,
    const float* __restrict__ u_cat, const float* __restrict__ u_trunc,
    float* __restrict__ params, double* __restrict__ accum)
{
    int b = blockIdx.x * 256 + threadIdx.x;
    float pr[9];
    float lq = prep_one(b, x, s, u_cat, u_trunc, pr);
    #pragma unroll
    for (int q = 0; q < 9; ++q) params[(size_t)b*9 + q] = pr[q];
    block_add(lq, &accum[0]);
}

__global__ void __launch_bounds__(256) k_fwd(
    const float* __restrict__ x, const float* __restrict__ params,
    double* __restrict__ accum)
{
    unsigned t = blockIdx.x * 256u + threadIdx.x;
    unsigned b = t / MF;
    unsigned m = t - b * MF;
    const float* pp = params + (size_t)b * 9;
    float pr[9];
    #pragma unroll
    for (int q = 0; q < 9; ++q) pr[q] = pp[q];
    float ll = fwd_one((int)b, (int)m, x, pr);
    block_add(ll, &accum[1]);
}

// Fallback if ws_size can't hold params: one thread per batch does everything.
__global__ void __launch_bounds__(256) k_mono(
    const float* __restrict__ x, const float* __restrict__ s,
    const float* __restrict__ u_cat, const float* __restrict__ u_trunc,
    double* __restrict__ accum)
{
    int b = blockIdx.x * 256 + threadIdx.x;
    float pr[9];
    float lq = prep_one(b, x, s, u_cat, u_trunc, pr);
    float ll = 0.0f;
    for (int m = 0; m < MF; ++m) ll += fwd_one(b, m, x, pr);
    block_add(lq, &accum[0]);
    block_add(ll, &accum[1]);
}

__global__ void k_fin(const double* __restrict__ accum, float* __restrict__ out)
{
    double term_lik = -accum[1] / ((double)BATCH_ * (double)(2*MF));
    double term_q   =  accum[0] / (double)BATCH_;
    out[0] = (float)(term_lik + term_q + 1.3862943611198906); // + log 4
}

extern "C" void kernel_launch(void* const* d_in, const int* in_sizes, int n_in,
                              void* d_out, int out_size, void* d_ws, size_t ws_size,
                              hipStream_t stream)
{
    (void)in_sizes; (void)n_in; (void)out_size;
    const float* x       = (const float*)d_in[0];
    const float* s       = (const float*)d_in[1];
    const float* u_cat   = (const float*)d_in[2];
    const float* u_trunc = (const float*)d_in[3];
    float* out = (float*)d_out;
    double* accum = (double*)d_ws;

    hipMemsetAsync(d_ws, 0, 256, stream);   // zero accumulators (ws is poisoned)

    size_t needed = 256 + (size_t)BATCH_ * 9 * sizeof(float);
    if (ws_size >= needed) {
        float* params = (float*)((char*)d_ws + 256);
        k_prep<<<BATCH_/256, 256, 0, stream>>>(x, s, u_cat, u_trunc, params, accum);
        k_fwd<<<(BATCH_*MF)/256, 256, 0, stream>>>(x, params, accum);
    } else {
        k_mono<<<BATCH_/256, 256, 0, stream>>>(x, s, u_cat, u_trunc, accum);
    }
    k_fin<<<1, 1, 0, stream>>>(accum, out);
}

// Round 2
// 269.739 us; speedup vs baseline: 1.6560x; 1.6560x over previous
//
#include <hip/hip_runtime.h>
#include <math.h>

#define NL 5
#define KM 5
#define MF 50
#define MH 25                 /* freqs per half, 2 per thread */
#define BATCH_ 131072
#define XROW (NL + 2*MF)      /* 105 */
#define SROW (KM*(2*NL+1))    /* 55  */
#define MU_F 1.2566370614359172e-06f
#define LOG2PI_F 1.8378770664093453f

__device__ __forceinline__ float rcpf_(float x)  { return __builtin_amdgcn_rcpf(x); }
__device__ __forceinline__ float sqrtf_(float x) { return __builtin_amdgcn_sqrtf(x); }
__device__ __forceinline__ float exp_(float x)   { return __expf(x); }
__device__ __forceinline__ float log_(float x)   { return __logf(x); }

// ndtr via A&S 7.1.26 erf (|eps| <= 1.5e-7); exact 0/1 saturation in tails.
__device__ __forceinline__ float ndtr_f(float x) {
    float z = fabsf(x) * 0.70710678f;
    float t = rcpf_(fmaf(0.3275911f, z, 1.0f));
    float poly = t*(0.254829592f + t*(-0.284496736f + t*(1.421413741f +
                 t*(-1.453152027f + t*1.061405429f))));
    float h = 0.5f * poly * exp_(-z*z);
    return x >= 0.0f ? 1.0f - h : h;
}

// ndtri via Giles' erfinv (branchless central/tail select).
// Caller must override p<=0 / p>=1 (poly NaNs at the exact endpoints).
__device__ __forceinline__ float ndtri_f(float p) {
    float x = fmaf(2.0f, p, -1.0f);
    float w = -log_((1.0f - x) * (1.0f + x));
    float wc = w - 2.5f;
    float pc =            2.81022636e-08f;
    pc = fmaf(pc, wc,     3.43273939e-07f);
    pc = fmaf(pc, wc,    -3.5233877e-06f);
    pc = fmaf(pc, wc,    -4.39150654e-06f);
    pc = fmaf(pc, wc,     0.00021858087f);
    pc = fmaf(pc, wc,    -0.00125372503f);
    pc = fmaf(pc, wc,    -0.00417768164f);
    pc = fmaf(pc, wc,     0.246640727f);
    pc = fmaf(pc, wc,     1.50140941f);
    float wt = sqrtf_(w) - 3.0f;
    float pt =           -0.000200214257f;
    pt = fmaf(pt, wt,     0.000100950558f);
    pt = fmaf(pt, wt,     0.00134934322f);
    pt = fmaf(pt, wt,    -0.00367342844f);
    pt = fmaf(pt, wt,     0.00573950773f);
    pt = fmaf(pt, wt,    -0.0076224613f);
    pt = fmaf(pt, wt,     0.00943887047f);
    pt = fmaf(pt, wt,     1.00167406f);
    pt = fmaf(pt, wt,     2.83297682f);
    float r = (w < 5.0f) ? pc : pt;
    return 1.41421356f * r * x;
}

// octant-reduced atan2, degree-11 odd minimax on [0,1] (~1e-6 rad)
__device__ __forceinline__ float atan2_f(float y, float x) {
    float ax = fabsf(x), ay = fabsf(y);
    float mx = fmaxf(ax, ay), mn = fminf(ax, ay);
    float a = mn * rcpf_(mx);
    float s = a * a;
    float r =            -0.01172120f;
    r = fmaf(r, s,        0.05265332f);
    r = fmaf(r, s,       -0.11643287f);
    r = fmaf(r, s,        0.19354346f);
    r = fmaf(r, s,       -0.33262347f);
    r = fmaf(r, s,        0.99997726f);
    r = r * a;
    r = (ay > ax)   ? (1.5707964f - r) : r;
    r = (x < 0.0f)  ? (3.1415927f - r) : r;
    return (y < 0.0f) ? -r : r;
}

// Block-wide sum of v -> one double atomicAdd per block.
__device__ __forceinline__ void block_add(float v, double* target) {
    __shared__ float red_[4];
    #pragma unroll
    for (int off = 32; off > 0; off >>= 1) v += __shfl_down(v, off, 64);
    __syncthreads();
    if ((threadIdx.x & 63) == 0) red_[threadIdx.x >> 6] = v;
    __syncthreads();
    if (threadIdx.x == 0)
        atomicAdd(target, (double)(red_[0] + red_[1] + red_[2] + red_[3]));
}

// Per-batch: mixture params, component draw, truncated samples, lq, and the
// 9 freq-independent constants. All are sqrt(MU/2)*10^(+-smp/2) forms:
//   pr[0]   = SQM * 10^(smp4/2)
//   pr[1+j] = 2*th_j * SQM * 10^(-smp_j/2)
//   pr[5+j] = SQM * 10^(+smp_j/2)
__device__ __forceinline__ float prep_one(
    int b, const float* __restrict__ x, const float* __restrict__ s,
    const float* __restrict__ u_cat, const float* __restrict__ u_trunc,
    float pr[9])
{
    const float* srow = s + (size_t)b * SROW;
    float loc[KM][NL], sig[KM][NL], pro[KM];
    float sqsum = 0.0f;
    #pragma unroll
    for (int k = 0; k < KM; ++k) {
        float v = srow[k*11 + 10];
        pro[k] = v * v;
        sqsum += pro[k];
    }
    float isq = 1.0f / sqsum;          // once/thread, keep precise
    #pragma unroll
    for (int k = 0; k < KM; ++k) pro[k] *= isq;
    #pragma unroll
    for (int k = 0; k < KM; ++k) {
        #pragma unroll
        for (int i = 0; i < NL; ++i) {
            loc[k][i] = 4.0f * rcpf_(1.0f + exp_(-srow[k*11 + i]));
            float v = srow[k*11 + 5 + i];
            sig[k][i] = fmaxf(v, 0.0f) + log_(1.0f + exp_(-fabsf(v)));
        }
    }
    // component draw
    float u = u_cat[b];
    float cum = 0.0f; int cnt = 0;
    #pragma unroll
    for (int k = 0; k < KM; ++k) { cum += pro[k]; if (u > cum) ++cnt; }
    int comp = cnt < KM-1 ? cnt : KM-1;
    float ls[NL], ss[NL];
    #pragma unroll
    for (int i = 0; i < NL; ++i) { ls[i] = loc[0][i]; ss[i] = sig[0][i]; }
    #pragma unroll
    for (int k = 1; k < KM; ++k) {
        bool sel = (k == comp);
        #pragma unroll
        for (int i = 0; i < NL; ++i) {
            ls[i] = sel ? loc[k][i] : ls[i];
            ss[i] = sel ? sig[k][i] : ss[i];
        }
    }
    // truncated-normal samples
    float smp[NL];
    #pragma unroll
    for (int i = 0; i < NL; ++i) {
        float invss = rcpf_(ss[i]);
        float a  = (0.1f - ls[i]) * invss;
        float bb = (3.9f - ls[i]) * invss;
        float Fa = ndtr_f(a), Fb = ndtr_f(bb);
        float p  = Fa + u_trunc[(size_t)b*NL + i] * (Fb - Fa);
        p = fminf(fmaxf(p, 0.0f), 1.0f);
        float z  = ndtri_f(p);
        if (p <= 0.0f) z = -INFINITY;     // match ocml/ndtri endpoint behavior
        if (p >= 1.0f) z =  INFINITY;
        float sq = fmaf(ss[i], z, ls[i]);
        smp[i] = fminf(fmaxf(sq, 0.1f), 3.9f);
    }
    // lq = logsumexp_k( log pro_k + sum_i truncnorm logpdf )
    float vals[KM]; float mx = -INFINITY;
    #pragma unroll
    for (int k = 0; k < KM; ++k) {
        float acc = log_(pro[k]);
        #pragma unroll
        for (int i = 0; i < NL; ++i) {
            float l = loc[k][i], sg = sig[k][i];
            float invs = rcpf_(sg);
            float zc = (smp[i] - l) * invs;
            float a_ = (-l) * invs;
            float b_ = (4.0f - l) * invs;
            float Z  = ndtr_f(b_) - ndtr_f(a_);     // >= ~0.29
            acc += fmaf(-0.5f, zc*zc, -0.5f*LOG2PI_F) - log_(sg * Z);
        }
        vals[k] = acc;
        mx = fmaxf(mx, acc);
    }
    float se = 0.0f;
    #pragma unroll
    for (int k = 0; k < KM; ++k) se += exp_(vals[k] - mx);
    float lq = mx + log_(se);
    // forward-model constants
    const float SQM = 7.9267442e-04f;     // sqrt(MU/2)
    const float HLN10 = 1.1512925f;       // 0.5*ln(10)
    pr[0] = SQM * exp_(HLN10 * smp[NL-1]);
    #pragma unroll
    for (int j = 0; j < NL-1; ++j) {
        float em = exp_(-HLN10 * smp[j]);           // 10^(-smp/2)
        float th = x[(size_t)b*XROW + j];
        pr[1+j] = 2.0f * th * SQM * em;
        pr[5+j] = SQM * rcpf_(em);
    }
    return lq;
}

// One (batch, freq): 4-layer MT recursion + both log-lik terms.
// t = sw*pr[1+j] <= ~0.112 -> e^{-t}e^{-it} by short Taylor (abs err <= 6e-7).
__device__ __forceinline__ float fwd_one(int b, int m,
    const float* __restrict__ x, const float pr[9])
{
    float ex = fmaf((float)m, 5.0f/49.0f, -2.0f);
    float w  = 6.2831853f * exp_(2.3025851f * ex);  // 2*pi*10^ex
    float sw = sqrtf_(w);
    float ZR = sw * pr[0];
    float ZC = ZR;
    #pragma unroll
    for (int j = NL-2; j >= 0; --j) {
        float wj = sw * pr[5+j];
        float t  = sw * pr[1+j];
        float t2 = t * t, t3 = t2 * t;
        float ejR = 1.0f - t + t3 * fmaf(-0.16666667f, t, 0.33333334f);
        float ejC = fmaf(t3, -0.33333334f, t2) - t;
        float s0 = wj + ZR, s1 = wj + ZC;
        float invden = rcpf_(fmaf(s0, s0, s1*s1));
        float wj2 = wj * wj;
        float rjR = (2.0f*wj2 - ZR*ZR - ZC*ZC) * invden;
        float rjC = (2.0f*wj*(ZR - ZC)) * invden;
        float reR = rjR*ejR - rjC*ejC;
        float reC = rjR*ejC + rjC*ejR;
        float o = 1.0f + reR;
        float invden2 = rcpf_(fmaf(o, o, reC*reC));
        float mag = fmaf(-reR, reR, fmaf(-reC, reC, 1.0f));
        float auxR = mag * invden2;
        float auxC = -2.0f * reC * invden2;
        ZR = wj * (auxR - auxC);
        ZC = wj * (auxC + auxR);
    }
    float absZ2 = fmaf(ZR, ZR, ZC*ZC);
    float aRes = log_(absZ2 * rcpf_(MU_F * w)) * 0.43429448f;
    float ph   = atan2_f(ZC, ZR);
    float oA = x[(size_t)b*XROW + NL + m];
    float oP = x[(size_t)b*XROW + NL + MF + m];
    float vA = (aRes - oA) * rcpf_(0.03f * fabsf(aRes));
    float vP = (ph   - oP) * rcpf_(0.03f * fabsf(ph));
    // -0.5vA^2 -0.5vP^2 - log(0.03|aRes|) - log(0.03|ph|) - LOG2PI
    // constants: -ln(9e-4) - LOG2PI = 5.1752387
    return fmaf(-0.5f, vA*vA, fmaf(-0.5f, vP*vP,
           5.1752387f - log_(fabsf(aRes * ph))));
}

__global__ void __launch_bounds__(256) k_prep(
    const float* __restrict__ x, const float* __restrict__ s,
    const float* __restrict__ u_cat, const float* __restrict__ u_trunc,
    float* __restrict__ params, double* __restrict__ accum)
{
    int b = blockIdx.x * 256 + threadIdx.x;
    float pr[9];
    float lq = prep_one(b, x, s, u_cat, u_trunc, pr);
    #pragma unroll
    for (int q = 0; q < 9; ++q) params[(size_t)q*BATCH_ + b] = pr[q];  // [9][B]
    block_add(lq, &accum[0]);
}

__global__ void __launch_bounds__(256) k_fwd(
    const float* __restrict__ x, const float* __restrict__ params,
    double* __restrict__ accum)
{
    unsigned t = blockIdx.x * 256u + threadIdx.x;
    unsigned b = t / MH;
    unsigned i = t - b * MH;
    float pr[9];
    #pragma unroll
    for (int q = 0; q < 9; ++q) pr[q] = params[(size_t)q*BATCH_ + b];
    // two independent frequency chains per thread (ILP)
    float ll = fwd_one((int)b, (int)i,      x, pr)
             + fwd_one((int)b, (int)i + MH, x, pr);
    block_add(ll, &accum[1]);
}

// Fallback if ws can't hold params.
__global__ void __launch_bounds__(256) k_mono(
    const float* __restrict__ x, const float* __restrict__ s,
    const float* __restrict__ u_cat, const float* __restrict__ u_trunc,
    double* __restrict__ accum)
{
    int b = blockIdx.x * 256 + threadIdx.x;
    float pr[9];
    float lq = prep_one(b, x, s, u_cat, u_trunc, pr);
    float ll = 0.0f;
    for (int m = 0; m < MF; ++m) ll += fwd_one(b, m, x, pr);
    block_add(lq, &accum[0]);
    block_add(ll, &accum[1]);
}

__global__ void k_fin(const double* __restrict__ accum, float* __restrict__ out)
{
    double term_lik = -accum[1] / ((double)BATCH_ * (double)(2*MF));
    double term_q   =  accum[0] / (double)BATCH_;
    out[0] = (float)(term_lik + term_q + 1.3862943611198906); // + log 4
}

extern "C" void kernel_launch(void* const* d_in, const int* in_sizes, int n_in,
                              void* d_out, int out_size, void* d_ws, size_t ws_size,
                              hipStream_t stream)
{
    (void)in_sizes; (void)n_in; (void)out_size;
    const float* x       = (const float*)d_in[0];
    const float* s       = (const float*)d_in[1];
    const float* u_cat   = (const float*)d_in[2];
    const float* u_trunc = (const float*)d_in[3];
    float* out = (float*)d_out;
    double* accum = (double*)d_ws;

    hipMemsetAsync(d_ws, 0, 256, stream);   // zero accumulators (ws is poisoned)

    size_t needed = 256 + (size_t)BATCH_ * 9 * sizeof(float);
    if (ws_size >= needed) {
        float* params = (float*)((char*)d_ws + 256);
        k_prep<<<BATCH_/256, 256, 0, stream>>>(x, s, u_cat, u_trunc, params, accum);
        k_fwd<<<(BATCH_*MH)/256, 256, 0, stream>>>(x, params, accum);
    } else {
        k_mono<<<BATCH_/256, 256, 0, stream>>>(x, s, u_cat, u_trunc, accum);
    }
    k_fin<<<1, 1, 0, stream>>>(accum, out);
}

// Round 3
// 176.569 us; speedup vs baseline: 2.5298x; 1.5277x over previous
//
#include <hip/hip_runtime.h>
#include <math.h>

#define NL 5
#define KM 5
#define MF 50
#define MH 25                 /* freqs per half, 2 per thread */
#define BATCH_ 131072
#define XROW (NL + 2*MF)      /* 105 */
#define SROW (KM*(2*NL+1))    /* 55  */
#define MU_F 1.2566370614359172e-06f
#define LOG2PI_F 1.8378770664093453f

#define NB_PREP (BATCH_*8/256)   /* 4096  */
#define NB_FWD  (BATCH_*MH/256)  /* 12800 */

__device__ __forceinline__ float rcpf_(float x)  { return __builtin_amdgcn_rcpf(x); }
__device__ __forceinline__ float sqrtf_(float x) { return __builtin_amdgcn_sqrtf(x); }
__device__ __forceinline__ float exp_(float x)   { return __expf(x); }
__device__ __forceinline__ float log_(float x)   { return __logf(x); }

// ndtr via A&S 7.1.26 erf (|eps| <= 1.5e-7)
__device__ __forceinline__ float ndtr_f(float x) {
    float z = fabsf(x) * 0.70710678f;
    float t = rcpf_(fmaf(0.3275911f, z, 1.0f));
    float poly = t*(0.254829592f + t*(-0.284496736f + t*(1.421413741f +
                 t*(-1.453152027f + t*1.061405429f))));
    float h = 0.5f * poly * exp_(-z*z);
    return x >= 0.0f ? 1.0f - h : h;
}

// ndtri via Giles' erfinv. Caller overrides exact endpoints.
__device__ __forceinline__ float ndtri_f(float p) {
    float x = fmaf(2.0f, p, -1.0f);
    float w = -log_((1.0f - x) * (1.0f + x));
    float wc = w - 2.5f;
    float pc =            2.81022636e-08f;
    pc = fmaf(pc, wc,     3.43273939e-07f);
    pc = fmaf(pc, wc,    -3.5233877e-06f);
    pc = fmaf(pc, wc,    -4.39150654e-06f);
    pc = fmaf(pc, wc,     0.00021858087f);
    pc = fmaf(pc, wc,    -0.00125372503f);
    pc = fmaf(pc, wc,    -0.00417768164f);
    pc = fmaf(pc, wc,     0.246640727f);
    pc = fmaf(pc, wc,     1.50140941f);
    float wt = sqrtf_(w) - 3.0f;
    float pt =           -0.000200214257f;
    pt = fmaf(pt, wt,     0.000100950558f);
    pt = fmaf(pt, wt,     0.00134934322f);
    pt = fmaf(pt, wt,    -0.00367342844f);
    pt = fmaf(pt, wt,     0.00573950773f);
    pt = fmaf(pt, wt,    -0.0076224613f);
    pt = fmaf(pt, wt,     0.00943887047f);
    pt = fmaf(pt, wt,     1.00167406f);
    pt = fmaf(pt, wt,     2.83297682f);
    float r = (w < 5.0f) ? pc : pt;
    return 1.41421356f * r * x;
}

// octant-reduced atan2, degree-11 odd minimax (~1e-6 rad)
__device__ __forceinline__ float atan2_f(float y, float x) {
    float ax = fabsf(x), ay = fabsf(y);
    float mx = fmaxf(ax, ay), mn = fminf(ax, ay);
    float a = mn * rcpf_(mx);
    float s = a * a;
    float r =            -0.01172120f;
    r = fmaf(r, s,        0.05265332f);
    r = fmaf(r, s,       -0.11643287f);
    r = fmaf(r, s,        0.19354346f);
    r = fmaf(r, s,       -0.33262347f);
    r = fmaf(r, s,        0.99997726f);
    r = r * a;
    r = (ay > ax)   ? (1.5707964f - r) : r;
    r = (x < 0.0f)  ? (3.1415927f - r) : r;
    return (y < 0.0f) ? -r : r;
}

// Block sum of v -> arr[blockIdx.x]  (NO atomics)
__device__ __forceinline__ void block_part(float v, float* __restrict__ arr) {
    __shared__ float red_[4];
    #pragma unroll
    for (int off = 32; off > 0; off >>= 1) v += __shfl_down(v, off, 64);
    __syncthreads();
    if ((threadIdx.x & 63) == 0) red_[threadIdx.x >> 6] = v;
    __syncthreads();
    if (threadIdx.x == 0)
        arr[blockIdx.x] = red_[0] + red_[1] + red_[2] + red_[3];
}

// ---------------- prep: 8 lanes per batch, lane i owns layer i -------------
// params layout [9][B]: pr0 = SQM*10^(smp4/2); pr[1+j]=2*th_j*SQM*10^(-smp_j/2);
// pr[5+j]=SQM*10^(smp_j/2)
__global__ void __launch_bounds__(256) k_prep8(
    const float* __restrict__ x, const float* __restrict__ s,
    const float* __restrict__ u_cat, const float* __restrict__ u_trunc,
    float* __restrict__ params, float* __restrict__ p_lq)
{
    unsigned t = blockIdx.x * 256u + threadIdx.x;
    unsigned b = t >> 3;
    unsigned i = t & 7;
    unsigned ii = i < 4 ? i : 4;          // lanes 5..7 duplicate layer 4 (no OOB)
    bool active = (i < NL);
    const float* srow = s + (size_t)b * SROW;

    float lc[KM], sg[KM], pro[KM];
    float sqsum = 0.0f;
    #pragma unroll
    for (int k = 0; k < KM; ++k) {
        float v = srow[k*11 + 10];
        pro[k] = v * v;
        sqsum += pro[k];
        lc[k] = 4.0f * rcpf_(1.0f + exp_(-srow[k*11 + ii]));
        float sv = srow[k*11 + 5 + ii];
        sg[k] = fmaxf(sv, 0.0f) + log_(1.0f + exp_(-fabsf(sv)));
    }
    float isq = rcpf_(sqsum);
    #pragma unroll
    for (int k = 0; k < KM; ++k) pro[k] *= isq;

    // component draw (redundant per lane, cheap)
    float u = u_cat[b];
    float cum = 0.0f; int cnt = 0;
    #pragma unroll
    for (int k = 0; k < KM; ++k) { cum += pro[k]; if (u > cum) ++cnt; }
    int comp = cnt < KM-1 ? cnt : KM-1;
    float ls = lc[0], ss = sg[0];
    #pragma unroll
    for (int k = 1; k < KM; ++k) {
        bool sel = (k == comp);
        ls = sel ? lc[k] : ls;
        ss = sel ? sg[k] : ss;
    }
    // truncated-normal sample for own layer
    float invss = rcpf_(ss);
    float a  = (0.1f - ls) * invss;
    float bb = (3.9f - ls) * invss;
    float Fa = ndtr_f(a), Fb = ndtr_f(bb);
    float p  = Fa + u_trunc[(size_t)b*NL + ii] * (Fb - Fa);
    p = fminf(fmaxf(p, 0.0f), 1.0f);
    float z = ndtri_f(p);
    if (p <= 0.0f) z = -INFINITY;
    if (p >= 1.0f) z =  INFINITY;
    float smp = fminf(fmaxf(fmaf(ss, z, ls), 0.1f), 3.9f);

    // own-layer terms of comp_lp for every k
    float c[KM];
    #pragma unroll
    for (int k = 0; k < KM; ++k) {
        float invs = rcpf_(sg[k]);
        float zc = (smp - lc[k]) * invs;
        float a_ = (-lc[k]) * invs;
        float b_ = (4.0f - lc[k]) * invs;
        float Z  = ndtr_f(b_) - ndtr_f(a_);   // >= ~0.29
        float v  = fmaf(-0.5f, zc*zc, -0.5f*LOG2PI_F) - log_(sg[k] * Z);
        c[k] = active ? v : 0.0f;
    }
    // sum own-layer terms across the 8-lane group
    #pragma unroll
    for (int k = 0; k < KM; ++k) {
        c[k] += __shfl_xor(c[k], 4, 8);
        c[k] += __shfl_xor(c[k], 2, 8);
        c[k] += __shfl_xor(c[k], 1, 8);
    }
    // logsumexp over k (redundant on all lanes)
    float mx = -INFINITY;
    float acc[KM];
    #pragma unroll
    for (int k = 0; k < KM; ++k) { acc[k] = log_(pro[k]) + c[k]; mx = fmaxf(mx, acc[k]); }
    float se = 0.0f;
    #pragma unroll
    for (int k = 0; k < KM; ++k) se += exp_(acc[k] - mx);
    float lq = mx + log_(se);

    // forward-model constants
    const float SQM = 7.9267442e-04f;     // sqrt(MU/2)
    const float HLN10 = 1.1512925f;       // 0.5*ln(10)
    float em  = exp_(-HLN10 * smp);       // 10^(-smp/2)
    float emi = SQM * rcpf_(em);          // SQM*10^(+smp/2)
    if (i < 4) {
        float th = x[(size_t)b*XROW + i];
        params[(size_t)(1+i)*BATCH_ + b] = 2.0f * th * SQM * em;
        params[(size_t)(5+i)*BATCH_ + b] = emi;
    } else if (i == 4) {
        params[b] = emi;                  // pr[0]
    }
    block_part(i == 0 ? lq : 0.0f, p_lq);
}

// ---------------- forward model ----------------
__device__ __forceinline__ float fwd_one(int b, int m,
    const float* __restrict__ x, const float pr[9])
{
    float ex = fmaf((float)m, 5.0f/49.0f, -2.0f);
    float w  = 6.2831853f * exp_(2.3025851f * ex);  // 2*pi*10^ex
    float sw = sqrtf_(w);
    float ZR = sw * pr[0];
    float ZC = ZR;
    #pragma unroll
    for (int j = NL-2; j >= 0; --j) {
        float wj = sw * pr[5+j];
        float t  = sw * pr[1+j];          // <= ~0.112
        float t2 = t * t, t3 = t2 * t;
        float ejR = 1.0f - t + t3 * fmaf(-0.16666667f, t, 0.33333334f);
        float ejC = fmaf(t3, -0.33333334f, t2) - t;
        float s0 = wj + ZR, s1 = wj + ZC;
        float invden = rcpf_(fmaf(s0, s0, s1*s1));
        float wj2 = wj * wj;
        float rjR = (2.0f*wj2 - ZR*ZR - ZC*ZC) * invden;
        float rjC = (2.0f*wj*(ZR - ZC)) * invden;
        float reR = rjR*ejR - rjC*ejC;
        float reC = rjR*ejC + rjC*ejR;
        float o = 1.0f + reR;
        float invden2 = rcpf_(fmaf(o, o, reC*reC));
        float mag = fmaf(-reR, reR, fmaf(-reC, reC, 1.0f));
        float auxR = mag * invden2;
        float auxC = -2.0f * reC * invden2;
        ZR = wj * (auxR - auxC);
        ZC = wj * (auxC + auxR);
    }
    float absZ2 = fmaf(ZR, ZR, ZC*ZC);
    float aRes = log_(absZ2 * rcpf_(MU_F * w)) * 0.43429448f;
    float ph   = atan2_f(ZC, ZR);
    float oA = x[(size_t)b*XROW + NL + m];
    float oP = x[(size_t)b*XROW + NL + MF + m];
    float vA = (aRes - oA) * rcpf_(0.03f * fabsf(aRes));
    float vP = (ph   - oP) * rcpf_(0.03f * fabsf(ph));
    // constants: -ln(9e-4) - LOG2PI = 5.1752387
    return fmaf(-0.5f, vA*vA, fmaf(-0.5f, vP*vP,
           5.1752387f - log_(fabsf(aRes * ph))));
}

__global__ void __launch_bounds__(256) k_fwd(
    const float* __restrict__ x, const float* __restrict__ params,
    float* __restrict__ p_ll)
{
    unsigned t = blockIdx.x * 256u + threadIdx.x;
    unsigned b = t / MH;
    unsigned i = t - b * MH;
    float pr[9];
    #pragma unroll
    for (int q = 0; q < 9; ++q) pr[q] = params[(size_t)q*BATCH_ + b];
    float ll = fwd_one((int)b, (int)i,      x, pr)
             + fwd_one((int)b, (int)i + MH, x, pr);
    block_part(ll, p_ll);
}

// ---------------- fallback (tiny ws): serial per-batch ----------------
__global__ void __launch_bounds__(256) k_mono(
    const float* __restrict__ x, const float* __restrict__ s,
    const float* __restrict__ u_cat, const float* __restrict__ u_trunc,
    float* __restrict__ p_lq, float* __restrict__ p_ll)
{
    int b = blockIdx.x * 256 + threadIdx.x;
    const float* srow = s + (size_t)b * SROW;
    float loc[KM][NL], sig[KM][NL], pro[KM];
    float sqsum = 0.0f;
    #pragma unroll
    for (int k = 0; k < KM; ++k) { float v = srow[k*11+10]; pro[k] = v*v; sqsum += pro[k]; }
    float isq = rcpf_(sqsum);
    #pragma unroll
    for (int k = 0; k < KM; ++k) pro[k] *= isq;
    #pragma unroll
    for (int k = 0; k < KM; ++k)
        #pragma unroll
        for (int i = 0; i < NL; ++i) {
            loc[k][i] = 4.0f * rcpf_(1.0f + exp_(-srow[k*11+i]));
            float v = srow[k*11+5+i];
            sig[k][i] = fmaxf(v, 0.0f) + log_(1.0f + exp_(-fabsf(v)));
        }
    float u = u_cat[b];
    float cum = 0.0f; int cnt = 0;
    #pragma unroll
    for (int k = 0; k < KM; ++k) { cum += pro[k]; if (u > cum) ++cnt; }
    int comp = cnt < KM-1 ? cnt : KM-1;
    float ls[NL], ss[NL];
    #pragma unroll
    for (int i = 0; i < NL; ++i) { ls[i] = loc[0][i]; ss[i] = sig[0][i]; }
    #pragma unroll
    for (int k = 1; k < KM; ++k) {
        bool sel = (k == comp);
        #pragma unroll
        for (int i = 0; i < NL; ++i) {
            ls[i] = sel ? loc[k][i] : ls[i];
            ss[i] = sel ? sig[k][i] : ss[i];
        }
    }
    float smp[NL];
    #pragma unroll
    for (int i = 0; i < NL; ++i) {
        float invss = rcpf_(ss[i]);
        float a  = (0.1f - ls[i]) * invss;
        float bb = (3.9f - ls[i]) * invss;
        float Fa = ndtr_f(a), Fb = ndtr_f(bb);
        float p  = Fa + u_trunc[(size_t)b*NL + i] * (Fb - Fa);
        p = fminf(fmaxf(p, 0.0f), 1.0f);
        float z  = ndtri_f(p);
        if (p <= 0.0f) z = -INFINITY;
        if (p >= 1.0f) z =  INFINITY;
        smp[i] = fminf(fmaxf(fmaf(ss[i], z, ls[i]), 0.1f), 3.9f);
    }
    float vals[KM]; float mx = -INFINITY;
    #pragma unroll
    for (int k = 0; k < KM; ++k) {
        float acc = log_(pro[k]);
        #pragma unroll
        for (int i = 0; i < NL; ++i) {
            float l = loc[k][i], sgv = sig[k][i];
            float invs = rcpf_(sgv);
            float zc = (smp[i] - l) * invs;
            float a_ = (-l) * invs;
            float b_ = (4.0f - l) * invs;
            float Z  = ndtr_f(b_) - ndtr_f(a_);
            acc += fmaf(-0.5f, zc*zc, -0.5f*LOG2PI_F) - log_(sgv * Z);
        }
        vals[k] = acc; mx = fmaxf(mx, acc);
    }
    float se = 0.0f;
    #pragma unroll
    for (int k = 0; k < KM; ++k) se += exp_(vals[k] - mx);
    float lq = mx + log_(se);
    const float SQM = 7.9267442e-04f;
    const float HLN10 = 1.1512925f;
    float pr[9];
    pr[0] = SQM * exp_(HLN10 * smp[NL-1]);
    #pragma unroll
    for (int j = 0; j < NL-1; ++j) {
        float em = exp_(-HLN10 * smp[j]);
        float th = x[(size_t)b*XROW + j];
        pr[1+j] = 2.0f * th * SQM * em;
        pr[5+j] = SQM * rcpf_(em);
    }
    float ll = 0.0f;
    for (int m = 0; m < MF; ++m) ll += fwd_one(b, m, x, pr);
    block_part(lq, p_lq);
    block_part(ll, p_ll);
}

// ---------------- final reduction ----------------
__global__ void __launch_bounds__(256) k_fin(
    const float* __restrict__ p_lq, int n_lq,
    const float* __restrict__ p_ll, int n_ll,
    float* __restrict__ out)
{
    int tid = threadIdx.x;
    double a0 = 0.0, a1 = 0.0;
    for (int j = tid; j < n_lq; j += 256) a0 += (double)p_lq[j];
    for (int j = tid; j < n_ll; j += 256) a1 += (double)p_ll[j];
    #pragma unroll
    for (int off = 32; off > 0; off >>= 1) {
        a0 += __shfl_down(a0, off, 64);
        a1 += __shfl_down(a1, off, 64);
    }
    __shared__ double r0[4], r1[4];
    if ((tid & 63) == 0) { r0[tid >> 6] = a0; r1[tid >> 6] = a1; }
    __syncthreads();
    if (tid == 0) {
        double A0 = r0[0]+r0[1]+r0[2]+r0[3];
        double A1 = r1[0]+r1[1]+r1[2]+r1[3];
        double term_lik = -A1 / ((double)BATCH_ * (double)(2*MF));
        double term_q   =  A0 / (double)BATCH_;
        out[0] = (float)(term_lik + term_q + 1.3862943611198906); // + log 4
    }
}

extern "C" void kernel_launch(void* const* d_in, const int* in_sizes, int n_in,
                              void* d_out, int out_size, void* d_ws, size_t ws_size,
                              hipStream_t stream)
{
    (void)in_sizes; (void)n_in; (void)out_size;
    const float* x       = (const float*)d_in[0];
    const float* s       = (const float*)d_in[1];
    const float* u_cat   = (const float*)d_in[2];
    const float* u_trunc = (const float*)d_in[3];
    float* out = (float*)d_out;

    // ws layout: p_lq[NB_PREP] | p_ll[NB_FWD] | params[9][B]
    float* p_lq   = (float*)d_ws;
    float* p_ll   = p_lq + NB_PREP;
    float* params = p_ll + NB_FWD;
    size_t needed = ((size_t)NB_PREP + NB_FWD + (size_t)BATCH_*9) * sizeof(float);

    if (ws_size >= needed) {
        k_prep8<<<NB_PREP, 256, 0, stream>>>(x, s, u_cat, u_trunc, params, p_lq);
        k_fwd  <<<NB_FWD,  256, 0, stream>>>(x, params, p_ll);
        k_fin  <<<1, 256, 0, stream>>>(p_lq, NB_PREP, p_ll, NB_FWD, out);
    } else {
        k_mono<<<BATCH_/256, 256, 0, stream>>>(x, s, u_cat, u_trunc, p_lq, p_ll);
        k_fin <<<1, 256, 0, stream>>>(p_lq, BATCH_/256, p_ll, BATCH_/256, out);
    }
}

// Round 4
// 166.818 us; speedup vs baseline: 2.6777x; 1.0585x over previous
//
#include <hip/hip_runtime.h>
#include <math.h>

#define NL 5
#define KM 5
#define MF 50
#define MHX 10                /* freq slots per batch; 5 freqs per thread */
#define ILP 5
#define BATCH_ 131072
#define XROW (NL + 2*MF)      /* 105 */
#define SROW (KM*(2*NL+1))    /* 55  */
#define MU_F 1.2566370614359172e-06f
#define LOG2PI_F 1.8378770664093453f

#define NB_PREP (BATCH_*8/256)    /* 4096 */
#define NB_FWD  (BATCH_*MHX/256)  /* 5120 */

__device__ __forceinline__ float rcpf_(float x)  { return __builtin_amdgcn_rcpf(x); }
__device__ __forceinline__ float sqrtf_(float x) { return __builtin_amdgcn_sqrtf(x); }
__device__ __forceinline__ float exp_(float x)   { return __expf(x); }
__device__ __forceinline__ float log_(float x)   { return __logf(x); }

// ndtr via A&S 7.1.26 erf (|eps| <= 1.5e-7)
__device__ __forceinline__ float ndtr_f(float x) {
    float z = fabsf(x) * 0.70710678f;
    float t = rcpf_(fmaf(0.3275911f, z, 1.0f));
    float poly = t*(0.254829592f + t*(-0.284496736f + t*(1.421413741f +
                 t*(-1.453152027f + t*1.061405429f))));
    float h = 0.5f * poly * exp_(-z*z);
    return x >= 0.0f ? 1.0f - h : h;
}

// ndtri via Giles' erfinv. Caller overrides exact endpoints.
__device__ __forceinline__ float ndtri_f(float p) {
    float x = fmaf(2.0f, p, -1.0f);
    float w = -log_((1.0f - x) * (1.0f + x));
    float wc = w - 2.5f;
    float pc =            2.81022636e-08f;
    pc = fmaf(pc, wc,     3.43273939e-07f);
    pc = fmaf(pc, wc,    -3.5233877e-06f);
    pc = fmaf(pc, wc,    -4.39150654e-06f);
    pc = fmaf(pc, wc,     0.00021858087f);
    pc = fmaf(pc, wc,    -0.00125372503f);
    pc = fmaf(pc, wc,    -0.00417768164f);
    pc = fmaf(pc, wc,     0.246640727f);
    pc = fmaf(pc, wc,     1.50140941f);
    float wt = sqrtf_(w) - 3.0f;
    float pt =           -0.000200214257f;
    pt = fmaf(pt, wt,     0.000100950558f);
    pt = fmaf(pt, wt,     0.00134934322f);
    pt = fmaf(pt, wt,    -0.00367342844f);
    pt = fmaf(pt, wt,     0.00573950773f);
    pt = fmaf(pt, wt,    -0.0076224613f);
    pt = fmaf(pt, wt,     0.00943887047f);
    pt = fmaf(pt, wt,     1.00167406f);
    pt = fmaf(pt, wt,     2.83297682f);
    float r = (w < 5.0f) ? pc : pt;
    return 1.41421356f * r * x;
}

// octant-reduced atan2, degree-11 odd minimax (~1e-6 rad)
__device__ __forceinline__ float atan2_f(float y, float x) {
    float ax = fabsf(x), ay = fabsf(y);
    float mx = fmaxf(ax, ay), mn = fminf(ax, ay);
    float a = mn * rcpf_(mx);
    float s = a * a;
    float r =            -0.01172120f;
    r = fmaf(r, s,        0.05265332f);
    r = fmaf(r, s,       -0.11643287f);
    r = fmaf(r, s,        0.19354346f);
    r = fmaf(r, s,       -0.33262347f);
    r = fmaf(r, s,        0.99997726f);
    r = r * a;
    r = (ay > ax)   ? (1.5707964f - r) : r;
    r = (x < 0.0f)  ? (3.1415927f - r) : r;
    return (y < 0.0f) ? -r : r;
}

// Block-wide sum; result valid on thread 0.
__device__ __forceinline__ float block_sum(float v) {
    __shared__ float red_[4];
    #pragma unroll
    for (int off = 32; off > 0; off >>= 1) v += __shfl_down(v, off, 64);
    __syncthreads();                      // WAR guard across repeated calls
    if ((threadIdx.x & 63) == 0) red_[threadIdx.x >> 6] = v;
    __syncthreads();
    return red_[0] + red_[1] + red_[2] + red_[3];
}

// ---------------- prep: 8 lanes per batch, lane i owns layer i -------------
// params layout [9][B]: pr0 = SQM*10^(smp4/2); pr[1+j]=2*th_j*SQM*10^(-smp_j/2);
// pr[5+j]=SQM*10^(smp_j/2)
__global__ void __launch_bounds__(256) k_prep8(
    const float* __restrict__ x, const float* __restrict__ s,
    const float* __restrict__ u_cat, const float* __restrict__ u_trunc,
    float* __restrict__ params, float* __restrict__ acc)
{
    unsigned t = blockIdx.x * 256u + threadIdx.x;
    unsigned b = t >> 3;
    unsigned i = t & 7;
    unsigned ii = i < 4 ? i : 4;          // lanes 5..7 duplicate layer 4
    bool active = (i < NL);
    const float* srow = s + (size_t)b * SROW;

    float lc[KM], sg[KM], pro[KM];
    float sqsum = 0.0f;
    #pragma unroll
    for (int k = 0; k < KM; ++k) {
        float v = srow[k*11 + 10];
        pro[k] = v * v;
        sqsum += pro[k];
        lc[k] = 4.0f * rcpf_(1.0f + exp_(-srow[k*11 + ii]));
        float sv = srow[k*11 + 5 + ii];
        sg[k] = fmaxf(sv, 0.0f) + log_(1.0f + exp_(-fabsf(sv)));
    }
    float isq = rcpf_(sqsum);
    #pragma unroll
    for (int k = 0; k < KM; ++k) pro[k] *= isq;

    // component draw (redundant per lane, cheap)
    float u = u_cat[b];
    float cum = 0.0f; int cnt = 0;
    #pragma unroll
    for (int k = 0; k < KM; ++k) { cum += pro[k]; if (u > cum) ++cnt; }
    int comp = cnt < KM-1 ? cnt : KM-1;
    float ls = lc[0], ss = sg[0];
    #pragma unroll
    for (int k = 1; k < KM; ++k) {
        bool sel = (k == comp);
        ls = sel ? lc[k] : ls;
        ss = sel ? sg[k] : ss;
    }
    // truncated-normal sample for own layer
    float invss = rcpf_(ss);
    float a  = (0.1f - ls) * invss;
    float bb = (3.9f - ls) * invss;
    float Fa = ndtr_f(a), Fb = ndtr_f(bb);
    float p  = Fa + u_trunc[(size_t)b*NL + ii] * (Fb - Fa);
    p = fminf(fmaxf(p, 0.0f), 1.0f);
    float z = ndtri_f(p);
    if (p <= 0.0f) z = -INFINITY;
    if (p >= 1.0f) z =  INFINITY;
    float smp = fminf(fmaxf(fmaf(ss, z, ls), 0.1f), 3.9f);

    // own-layer terms of comp_lp for every k
    float c[KM];
    #pragma unroll
    for (int k = 0; k < KM; ++k) {
        float invs = rcpf_(sg[k]);
        float zc = (smp - lc[k]) * invs;
        float a_ = (-lc[k]) * invs;
        float b_ = (4.0f - lc[k]) * invs;
        float Z  = ndtr_f(b_) - ndtr_f(a_);   // >= ~0.29
        float v  = fmaf(-0.5f, zc*zc, -0.5f*LOG2PI_F) - log_(sg[k] * Z);
        c[k] = active ? v : 0.0f;
    }
    #pragma unroll
    for (int k = 0; k < KM; ++k) {
        c[k] += __shfl_xor(c[k], 4, 8);
        c[k] += __shfl_xor(c[k], 2, 8);
        c[k] += __shfl_xor(c[k], 1, 8);
    }
    float mx = -INFINITY;
    float av[KM];
    #pragma unroll
    for (int k = 0; k < KM; ++k) { av[k] = log_(pro[k]) + c[k]; mx = fmaxf(mx, av[k]); }
    float se = 0.0f;
    #pragma unroll
    for (int k = 0; k < KM; ++k) se += exp_(av[k] - mx);
    float lq = mx + log_(se);

    const float SQM = 7.9267442e-04f;     // sqrt(MU/2)
    const float HLN10 = 1.1512925f;       // 0.5*ln(10)
    float em  = exp_(-HLN10 * smp);       // 10^(-smp/2)
    float emi = SQM * rcpf_(em);          // SQM*10^(+smp/2)
    if (i < 4) {
        float th = x[(size_t)b*XROW + i];
        params[(size_t)(1+i)*BATCH_ + b] = 2.0f * th * SQM * em;
        params[(size_t)(5+i)*BATCH_ + b] = emi;
    } else if (i == 4) {
        params[b] = emi;                  // pr[0]
    }
    float tot = block_sum(i == 0 ? lq : 0.0f);
    if (threadIdx.x == 0) atomicAdd(&acc[256 + (blockIdx.x & 255)], tot);
}

// ---------------- forward model ----------------
// sw = sqrt(2*pi)*10^(ex/2);  log10(absZ2/(MU*w)) = 0.4342945*ln(absZ2)+5.1026102-ex
__device__ __forceinline__ float fwd_one(int b, int m,
    const float* __restrict__ x, const float pr[9])
{
    float ex = fmaf((float)m, 0.10204082f, -2.0f);
    float sw = 2.5066283f * exp_(1.1512925f * ex);
    float ZR = sw * pr[0];
    float ZC = ZR;
    #pragma unroll
    for (int j = NL-2; j >= 0; --j) {
        float wj = sw * pr[5+j];
        float t  = sw * pr[1+j];          // <= ~0.112
        float t2 = t * t, t3 = t2 * t;
        float ejR = 1.0f - t + t3 * fmaf(-0.16666667f, t, 0.33333334f);
        float ejC = fmaf(t3, -0.33333334f, t2) - t;
        float s0 = wj + ZR, s1 = wj + ZC;
        float invden = rcpf_(fmaf(s0, s0, s1*s1));
        float wj2 = wj * wj;
        float rjR = (2.0f*wj2 - ZR*ZR - ZC*ZC) * invden;
        float rjC = (2.0f*wj*(ZR - ZC)) * invden;
        float reR = rjR*ejR - rjC*ejC;
        float reC = rjR*ejC + rjC*ejR;
        float o = 1.0f + reR;
        float invden2 = rcpf_(fmaf(o, o, reC*reC));
        float mag = fmaf(-reR, reR, fmaf(-reC, reC, 1.0f));
        float auxR = mag * invden2;
        float auxC = -2.0f * reC * invden2;
        ZR = wj * (auxR - auxC);
        ZC = wj * (auxC + auxR);
    }
    float absZ2 = fmaf(ZR, ZR, ZC*ZC);
    float aRes = fmaf(0.43429448f, log_(absZ2), 5.1026102f - ex);
    float ph   = atan2_f(ZC, ZR);
    float oA = x[(size_t)b*XROW + NL + m];
    float oP = x[(size_t)b*XROW + NL + MF + m];
    float vA = (aRes - oA) * rcpf_(0.03f * fabsf(aRes));
    float vP = (ph   - oP) * rcpf_(0.03f * fabsf(ph));
    // constants: -ln(9e-4) - LOG2PI = 5.1752387
    return fmaf(-0.5f, vA*vA, fmaf(-0.5f, vP*vP,
           5.1752387f - log_(fabsf(aRes * ph))));
}

__global__ void __launch_bounds__(256, 4) k_fwd(
    const float* __restrict__ x, const float* __restrict__ params,
    float* __restrict__ acc)
{
    unsigned t = blockIdx.x * 256u + threadIdx.x;
    unsigned b = t / MHX;
    unsigned i = t - b * MHX;
    float pr[9];
    #pragma unroll
    for (int q = 0; q < 9; ++q) pr[q] = params[(size_t)q*BATCH_ + b];
    float ll = 0.0f;
    #pragma unroll
    for (int q = 0; q < ILP; ++q)
        ll += fwd_one((int)b, (int)(i + MHX*q), x, pr);   // 5 independent chains
    float tot = block_sum(ll);
    if (threadIdx.x == 0) atomicAdd(&acc[blockIdx.x & 255], tot);
}

// ---------------- fallback (tiny ws): serial per-batch ----------------
__global__ void __launch_bounds__(256) k_mono(
    const float* __restrict__ x, const float* __restrict__ s,
    const float* __restrict__ u_cat, const float* __restrict__ u_trunc,
    float* __restrict__ acc)
{
    int b = blockIdx.x * 256 + threadIdx.x;
    const float* srow = s + (size_t)b * SROW;
    float loc[KM][NL], sig[KM][NL], pro[KM];
    float sqsum = 0.0f;
    #pragma unroll
    for (int k = 0; k < KM; ++k) { float v = srow[k*11+10]; pro[k] = v*v; sqsum += pro[k]; }
    float isq = rcpf_(sqsum);
    #pragma unroll
    for (int k = 0; k < KM; ++k) pro[k] *= isq;
    #pragma unroll
    for (int k = 0; k < KM; ++k)
        #pragma unroll
        for (int i = 0; i < NL; ++i) {
            loc[k][i] = 4.0f * rcpf_(1.0f + exp_(-srow[k*11+i]));
            float v = srow[k*11+5+i];
            sig[k][i] = fmaxf(v, 0.0f) + log_(1.0f + exp_(-fabsf(v)));
        }
    float u = u_cat[b];
    float cum = 0.0f; int cnt = 0;
    #pragma unroll
    for (int k = 0; k < KM; ++k) { cum += pro[k]; if (u > cum) ++cnt; }
    int comp = cnt < KM-1 ? cnt : KM-1;
    float ls[NL], ss[NL];
    #pragma unroll
    for (int i = 0; i < NL; ++i) { ls[i] = loc[0][i]; ss[i] = sig[0][i]; }
    #pragma unroll
    for (int k = 1; k < KM; ++k) {
        bool sel = (k == comp);
        #pragma unroll
        for (int i = 0; i < NL; ++i) {
            ls[i] = sel ? loc[k][i] : ls[i];
            ss[i] = sel ? sig[k][i] : ss[i];
        }
    }
    float smp[NL];
    #pragma unroll
    for (int i = 0; i < NL; ++i) {
        float invss = rcpf_(ss[i]);
        float a  = (0.1f - ls[i]) * invss;
        float bb = (3.9f - ls[i]) * invss;
        float Fa = ndtr_f(a), Fb = ndtr_f(bb);
        float p  = Fa + u_trunc[(size_t)b*NL + i] * (Fb - Fa);
        p = fminf(fmaxf(p, 0.0f), 1.0f);
        float z  = ndtri_f(p);
        if (p <= 0.0f) z = -INFINITY;
        if (p >= 1.0f) z =  INFINITY;
        smp[i] = fminf(fmaxf(fmaf(ss[i], z, ls[i]), 0.1f), 3.9f);
    }
    float vals[KM]; float mx = -INFINITY;
    #pragma unroll
    for (int k = 0; k < KM; ++k) {
        float av = log_(pro[k]);
        #pragma unroll
        for (int i = 0; i < NL; ++i) {
            float l = loc[k][i], sgv = sig[k][i];
            float invs = rcpf_(sgv);
            float zc = (smp[i] - l) * invs;
            float a_ = (-l) * invs;
            float b_ = (4.0f - l) * invs;
            float Z  = ndtr_f(b_) - ndtr_f(a_);
            av += fmaf(-0.5f, zc*zc, -0.5f*LOG2PI_F) - log_(sgv * Z);
        }
        vals[k] = av; mx = fmaxf(mx, av);
    }
    float se = 0.0f;
    #pragma unroll
    for (int k = 0; k < KM; ++k) se += exp_(vals[k] - mx);
    float lq = mx + log_(se);
    const float SQM = 7.9267442e-04f;
    const float HLN10 = 1.1512925f;
    float pr[9];
    pr[0] = SQM * exp_(HLN10 * smp[NL-1]);
    #pragma unroll
    for (int j = 0; j < NL-1; ++j) {
        float em = exp_(-HLN10 * smp[j]);
        float th = x[(size_t)b*XROW + j];
        pr[1+j] = 2.0f * th * SQM * em;
        pr[5+j] = SQM * rcpf_(em);
    }
    float ll = 0.0f;
    for (int m = 0; m < MF; ++m) ll += fwd_one(b, m, x, pr);
    float t0 = block_sum(ll);
    if (threadIdx.x == 0) atomicAdd(&acc[blockIdx.x & 255], t0);
    float t1 = block_sum(lq);
    if (threadIdx.x == 0) atomicAdd(&acc[256 + (blockIdx.x & 255)], t1);
}

// ---------------- final reduction: 512 floats -> scalar ----------------
__global__ void __launch_bounds__(256) k_fin(
    const float* __restrict__ acc, float* __restrict__ out)
{
    int tid = threadIdx.x;
    double a1 = (double)acc[tid];          // ll partials
    double a0 = (double)acc[256 + tid];    // lq partials
    #pragma unroll
    for (int off = 32; off > 0; off >>= 1) {
        a0 += __shfl_down(a0, off, 64);
        a1 += __shfl_down(a1, off, 64);
    }
    __shared__ double r0[4], r1[4];
    if ((tid & 63) == 0) { r0[tid >> 6] = a0; r1[tid >> 6] = a1; }
    __syncthreads();
    if (tid == 0) {
        double A0 = r0[0]+r0[1]+r0[2]+r0[3];
        double A1 = r1[0]+r1[1]+r1[2]+r1[3];
        double term_lik = -A1 / ((double)BATCH_ * (double)(2*MF));
        double term_q   =  A0 / (double)BATCH_;
        out[0] = (float)(term_lik + term_q + 1.3862943611198906); // + log 4
    }
}

extern "C" void kernel_launch(void* const* d_in, const int* in_sizes, int n_in,
                              void* d_out, int out_size, void* d_ws, size_t ws_size,
                              hipStream_t stream)
{
    (void)in_sizes; (void)n_in; (void)out_size;
    const float* x       = (const float*)d_in[0];
    const float* s       = (const float*)d_in[1];
    const float* u_cat   = (const float*)d_in[2];
    const float* u_trunc = (const float*)d_in[3];
    float* out = (float*)d_out;

    float* acc    = (float*)d_ws;                 // 512 floats
    float* params = (float*)((char*)d_ws + 2048); // [9][B]
    size_t needed = 2048 + (size_t)BATCH_ * 9 * sizeof(float);

    hipMemsetAsync(d_ws, 0, 2048, stream);        // zero the atomic accumulators

    if (ws_size >= needed) {
        k_prep8<<<NB_PREP, 256, 0, stream>>>(x, s, u_cat, u_trunc, params, acc);
        k_fwd  <<<NB_FWD,  256, 0, stream>>>(x, params, acc);
    } else {
        k_mono<<<BATCH_/256, 256, 0, stream>>>(x, s, u_cat, u_trunc, acc);
    }
    k_fin<<<1, 256, 0, stream>>>(acc, out);
}